// Round 2
// baseline (465.581 us; speedup 1.0000x reference)
//
#include <hip/hip_runtime.h>
#include <hip/hip_bf16.h>
#include <cstdint>

#define B_ 4
#define T_ 2048
#define C_ 768
#define H_ 12
#define D_ 64
#define MLP_ 3072
#define BT_ (B_*T_)

typedef __hip_bfloat16 hbf;
typedef __bf16 bf16_t;
typedef bf16_t bf16x8 __attribute__((ext_vector_type(8)));
typedef float f32x4 __attribute__((ext_vector_type(4)));

static __device__ __forceinline__ void load_lds16(const void* g, void* l) {
    __builtin_amdgcn_global_load_lds(
        (const __attribute__((address_space(1))) unsigned int*)g,
        (__attribute__((address_space(3))) unsigned int*)l, 16, 0, 0);
}

// ---------------- weight packing ----------------
// WqkvT[(t*768 + h*64 + d)*768 + c] = W_t[h][c][d]
__global__ __launch_bounds__(256) void pack_qkv_kernel(
    const float* __restrict__ Wq, const float* __restrict__ Wk,
    const float* __restrict__ Wv, hbf* __restrict__ dst)
{
    int idx = blockIdx.x * 256 + threadIdx.x;   // [0, 3*768*768)
    int c = idx % C_;
    int n = idx / C_;           // [0, 2304)
    int t = n / C_;             // 0,1,2
    int r = n - t * C_;
    int h = r >> 6, d = r & 63;
    const float* W = (t == 0) ? Wq : (t == 1) ? Wk : Wv;
    dst[idx] = __float2bfloat16(W[((size_t)h * C_ + c) * D_ + d]);
}

// dst[s*R + r] = src[r*S + s]   (src is [R][S] f32, dst is [S][R] bf16)
__global__ __launch_bounds__(256) void transpose_cast_kernel(
    const float* __restrict__ src, hbf* __restrict__ dst, int R, int S)
{
    int idx = blockIdx.x * 256 + threadIdx.x;
    if (idx >= R * S) return;
    int r = idx % R;
    int s = idx / R;
    dst[idx] = __float2bfloat16(src[(size_t)r * S + s]);
}

// ---------------- layernorm (row = 768) ----------------
__global__ __launch_bounds__(256) void ln_kernel(
    const float* __restrict__ x, const float* __restrict__ g,
    const float* __restrict__ bb, hbf* __restrict__ out)
{
    __shared__ float red[8];
    const int row = blockIdx.x;
    const float* xr = x + (size_t)row * C_;
    const int t = threadIdx.x;
    float v0 = xr[t], v1 = xr[t + 256], v2 = xr[t + 512];
    float s = v0 + v1 + v2;
    float s2 = v0 * v0 + v1 * v1 + v2 * v2;
#pragma unroll
    for (int m = 1; m < 64; m <<= 1) {
        s  += __shfl_xor(s,  m, 64);
        s2 += __shfl_xor(s2, m, 64);
    }
    if ((t & 63) == 0) { red[t >> 6] = s; red[4 + (t >> 6)] = s2; }
    __syncthreads();
    float S  = red[0] + red[1] + red[2] + red[3];
    float S2 = red[4] + red[5] + red[6] + red[7];
    float mu  = S * (1.0f / C_);
    float var = S2 * (1.0f / C_) - mu * mu;
    float inv = rsqrtf(var + 1e-6f);
    hbf* orow = out + (size_t)row * C_;
    orow[t]       = __float2bfloat16((v0 - mu) * inv * g[t]       + bb[t]);
    orow[t + 256] = __float2bfloat16((v1 - mu) * inv * g[t + 256] + bb[t + 256]);
    orow[t + 512] = __float2bfloat16((v2 - mu) * inv * g[t + 512] + bb[t + 512]);
}

// ---------------- GEMM: C[M,N] = A[M,K](bf16) * Bt[N,K](bf16)^T ----------------
// EPI 0: bf16 out plain
// EPI 1: f32 out = acc + bias[col] + resid[row*N+col]
// EPI 2: bf16 out = gelu(acc + bias[col])   (exact erf)
// EPI 3: QKV scatter (N=2304): q scaled, k plain, v transposed [bh][d][t]
template<int EPI>
__global__ __launch_bounds__(256, 2) void gemm_kernel(
    const hbf* __restrict__ A, const hbf* __restrict__ Bt,
    float* __restrict__ outF, hbf* __restrict__ outH,
    const float* __restrict__ bias, const float* __restrict__ resid,
    int M, int N, int K,
    hbf* __restrict__ qb, hbf* __restrict__ kb, hbf* __restrict__ vb,
    float scale)
{
    __shared__ hbf sA[128 * 32];
    __shared__ hbf sB[128 * 32];
    const int tid = threadIdx.x;
    const int lane = tid & 63;
    const int wid = tid >> 6;
    const int wm = wid >> 1, wn = wid & 1;
    const int lr = lane & 15, hg = lane >> 4;
    const int row0 = blockIdx.y * 128;
    const int col0 = blockIdx.x * 128;

    f32x4 acc[4][4] = {};

    // staging: 8KB per tile = 512 x 16B chunks; thread t takes chunks t and t+256
    const int c0 = tid * 16;
    const int c1 = c0 + 4096;
    const int r0s = c0 >> 6, cb0 = c0 & 63;
    const int r1s = c1 >> 6, cb1 = c1 & 63;
    char* lA0 = (char*)sA + wid * 1024;
    char* lA1 = (char*)sA + 4096 + wid * 1024;
    char* lB0 = (char*)sB + wid * 1024;
    char* lB1 = (char*)sB + 4096 + wid * 1024;
    const char* gA = (const char*)(A + (size_t)row0 * K);
    const char* gB = (const char*)(Bt + (size_t)col0 * K);
    const int Kb = K * 2;

    for (int k0 = 0; k0 < K; k0 += 32) {
        const int kb2 = k0 * 2;
        load_lds16(gA + (size_t)r0s * Kb + kb2 + cb0, lA0);
        load_lds16(gA + (size_t)r1s * Kb + kb2 + cb1, lA1);
        load_lds16(gB + (size_t)r0s * Kb + kb2 + cb0, lB0);
        load_lds16(gB + (size_t)r1s * Kb + kb2 + cb1, lB1);
        __syncthreads();

        bf16x8 af[4], bfr[4];
#pragma unroll
        for (int m = 0; m < 4; ++m)
            af[m] = *(const bf16x8*)((const char*)sA + (wm * 64 + m * 16 + lr) * 64 + hg * 16);
#pragma unroll
        for (int n = 0; n < 4; ++n)
            bfr[n] = *(const bf16x8*)((const char*)sB + (wn * 64 + n * 16 + lr) * 64 + hg * 16);
#pragma unroll
        for (int m = 0; m < 4; ++m)
#pragma unroll
            for (int n = 0; n < 4; ++n)
                acc[m][n] = __builtin_amdgcn_mfma_f32_16x16x32_bf16(af[m], bfr[n], acc[m][n], 0, 0, 0);
        __syncthreads();
    }

#pragma unroll
    for (int m = 0; m < 4; ++m) {
#pragma unroll
        for (int n = 0; n < 4; ++n) {
#pragma unroll
            for (int j = 0; j < 4; ++j) {
                int row = row0 + wm * 64 + m * 16 + hg * 4 + j;
                int col = col0 + wn * 64 + n * 16 + lr;
                float v = acc[m][n][j];
                if constexpr (EPI == 0) {
                    outH[(size_t)row * N + col] = __float2bfloat16(v);
                } else if constexpr (EPI == 1) {
                    outF[(size_t)row * N + col] = v + bias[col] + resid[(size_t)row * N + col];
                } else if constexpr (EPI == 2) {
                    float tt = v + bias[col];
                    float ge = 0.5f * tt * (1.0f + erff(tt * 0.70710678118654752f));
                    outH[(size_t)row * N + col] = __float2bfloat16(ge);
                } else {
                    int typ = col / C_;
                    int rr = col - typ * C_;
                    int h = rr >> 6, d = rr & 63;
                    int b = row >> 11, t = row & (T_ - 1);
                    size_t bh = (size_t)b * H_ + h;
                    if (typ == 0)      qb[(bh * T_ + t) * D_ + d] = __float2bfloat16(v * scale);
                    else if (typ == 1) kb[(bh * T_ + t) * D_ + d] = __float2bfloat16(v);
                    else               vb[(bh * D_ + d) * T_ + t] = __float2bfloat16(v);
                }
            }
        }
    }
}

// ---------------- flash attention ----------------
// grid (T/128, B*H); 4 waves x 32 q-rows. q pre-scaled. vT is [bh][d][t].
__global__ __launch_bounds__(256, 2) void attn_kernel(
    const hbf* __restrict__ qg, const hbf* __restrict__ kg,
    const hbf* __restrict__ vg, hbf* __restrict__ outA)
{
    __shared__ hbf sK[64 * 64];       // [s][d]
    __shared__ hbf sV[64 * 64];       // [d][s]
    __shared__ hbf sP[4 * 32 * 64];   // per wave [r][s]
    const int tid = threadIdx.x, lane = tid & 63, wid = tid >> 6;
    const int lr = lane & 15, hg = lane >> 4;
    const int bh = blockIdx.y;
    const int b = bh / H_, h = bh - b * H_;
    const int wr0 = blockIdx.x * 128 + wid * 32;
    const hbf* qbh = qg + (size_t)bh * T_ * D_;
    const hbf* kbh = kg + (size_t)bh * T_ * D_;
    const hbf* vbh = vg + (size_t)bh * D_ * T_;

    bf16x8 a_q[2][2];
#pragma unroll
    for (int m = 0; m < 2; ++m)
#pragma unroll
        for (int kf = 0; kf < 2; ++kf)
            a_q[m][kf] = *(const bf16x8*)(qbh + (size_t)(wr0 + m * 16 + lr) * D_ + kf * 32 + hg * 8);

    f32x4 o[2][4] = {};
    float mrun[2][4], lrun[2][4];
#pragma unroll
    for (int m = 0; m < 2; ++m)
#pragma unroll
        for (int j = 0; j < 4; ++j) { mrun[m][j] = -1e30f; lrun[m][j] = 0.0f; }

    const int c0 = tid * 16, c1 = c0 + 4096;
    const int r0s = c0 >> 7, cb0 = c0 & 127;
    const int r1s = c1 >> 7, cb1 = c1 & 127;
    char* lK0 = (char*)sK + wid * 1024; char* lK1 = (char*)sK + 4096 + wid * 1024;
    char* lV0 = (char*)sV + wid * 1024; char* lV1 = (char*)sV + 4096 + wid * 1024;
    hbf* sPw = sP + wid * (32 * 64);

    for (int s0 = 0; s0 < T_; s0 += 64) {
        load_lds16((const char*)(kbh + (size_t)(s0 + r0s) * D_) + cb0, lK0);
        load_lds16((const char*)(kbh + (size_t)(s0 + r1s) * D_) + cb1, lK1);
        load_lds16((const char*)(vbh + (size_t)r0s * T_ + s0) + cb0, lV0);
        load_lds16((const char*)(vbh + (size_t)r1s * T_ + s0) + cb1, lV1);
        __syncthreads();

        f32x4 sacc[2][4] = {};
#pragma unroll
        for (int n = 0; n < 4; ++n) {
#pragma unroll
            for (int kf = 0; kf < 2; ++kf) {
                bf16x8 bk = *(const bf16x8*)((const char*)sK + (n * 16 + lr) * 128 + kf * 64 + hg * 16);
#pragma unroll
                for (int m = 0; m < 2; ++m)
                    sacc[m][n] = __builtin_amdgcn_mfma_f32_16x16x32_bf16(a_q[m][kf], bk, sacc[m][n], 0, 0, 0);
            }
        }
        // online softmax
        float fac[2][4];
#pragma unroll
        for (int m = 0; m < 2; ++m) {
#pragma unroll
            for (int j = 0; j < 4; ++j) {
                float t = fmaxf(fmaxf(sacc[m][0][j], sacc[m][1][j]),
                                fmaxf(sacc[m][2][j], sacc[m][3][j]));
                t = fmaxf(t, __shfl_xor(t, 1, 64));
                t = fmaxf(t, __shfl_xor(t, 2, 64));
                t = fmaxf(t, __shfl_xor(t, 4, 64));
                t = fmaxf(t, __shfl_xor(t, 8, 64));
                float nm = fmaxf(mrun[m][j], t);
                fac[m][j] = __expf(mrun[m][j] - nm);
                mrun[m][j] = nm;
            }
        }
        float psum[2][4] = {};
#pragma unroll
        for (int m = 0; m < 2; ++m)
#pragma unroll
            for (int n = 0; n < 4; ++n)
#pragma unroll
                for (int j = 0; j < 4; ++j) {
                    float p = __expf(sacc[m][n][j] - mrun[m][j]);
                    psum[m][j] += p;
                    sPw[(m * 16 + hg * 4 + j) * 64 + n * 16 + lr] = __float2bfloat16(p);
                }
#pragma unroll
        for (int m = 0; m < 2; ++m)
#pragma unroll
            for (int j = 0; j < 4; ++j) {
                float s = psum[m][j];
                s += __shfl_xor(s, 1, 64);
                s += __shfl_xor(s, 2, 64);
                s += __shfl_xor(s, 4, 64);
                s += __shfl_xor(s, 8, 64);
                lrun[m][j] = lrun[m][j] * fac[m][j] + s;
#pragma unroll
                for (int nd = 0; nd < 4; ++nd)
                    o[m][nd][j] *= fac[m][j];
            }
        __syncthreads();   // P writes visible (and keeps compiler from reordering the punned reads)
        // PV
#pragma unroll
        for (int kf = 0; kf < 2; ++kf) {
            bf16x8 ap[2];
#pragma unroll
            for (int m = 0; m < 2; ++m)
                ap[m] = *(const bf16x8*)((const char*)sPw + (m * 16 + lr) * 128 + kf * 64 + hg * 16);
#pragma unroll
            for (int nd = 0; nd < 4; ++nd) {
                bf16x8 bv = *(const bf16x8*)((const char*)sV + (nd * 16 + lr) * 128 + kf * 64 + hg * 16);
#pragma unroll
                for (int m = 0; m < 2; ++m)
                    o[m][nd] = __builtin_amdgcn_mfma_f32_16x16x32_bf16(ap[m], bv, o[m][nd], 0, 0, 0);
            }
        }
        __syncthreads();
    }

#pragma unroll
    for (int m = 0; m < 2; ++m)
#pragma unroll
        for (int nd = 0; nd < 4; ++nd)
#pragma unroll
            for (int j = 0; j < 4; ++j) {
                int row = wr0 + m * 16 + hg * 4 + j;
                int col = nd * 16 + lr;
                float val = o[m][nd][j] / lrun[m][j];
                outA[((size_t)(b * T_ + row)) * C_ + h * D_ + col] = __float2bfloat16(val);
            }
}

// ---------------- launch ----------------
extern "C" void kernel_launch(void* const* d_in, const int* in_sizes, int n_in,
                              void* d_out, int out_size, void* d_ws, size_t ws_size,
                              hipStream_t stream)
{
    const float* x    = (const float*)d_in[0];
    const float* Wq   = (const float*)d_in[1];
    const float* Wk   = (const float*)d_in[2];
    const float* Wv   = (const float*)d_in[3];
    const float* Wo   = (const float*)d_in[4];
    const float* bo   = (const float*)d_in[5];
    const float* ln1g = (const float*)d_in[6];
    const float* ln1b = (const float*)d_in[7];
    const float* ln2g = (const float*)d_in[8];
    const float* ln2b = (const float*)d_in[9];
    const float* W1   = (const float*)d_in[10];
    const float* b1   = (const float*)d_in[11];
    const float* W2   = (const float*)d_in[12];
    const float* b2   = (const float*)d_in[13];
    float* out = (float*)d_out;
    char* ws = (char*)d_ws;

    // workspace layout (bytes); h1 overlays xn..vb, yln overlays attnB
    hbf*  xn    = (hbf*)(ws + 0);            // 12,582,912
    hbf*  WqkvT = (hbf*)(ws + 12582912);     //  3,538,944
    hbf*  qb    = (hbf*)(ws + 16121856);     // 12,582,912
    hbf*  kb    = (hbf*)(ws + 28704768);     // 12,582,912
    hbf*  vb    = (hbf*)(ws + 41287680);     // 12,582,912  (end 53,870,592)
    hbf*  h1    = (hbf*)(ws + 0);            // 50,331,648  (overlays: dead by MLP)
    hbf*  attnB = (hbf*)(ws + 53870592);     // 12,582,912
    hbf*  yln   = (hbf*)(ws + 53870592);     // overlays attnB (dead after proj)
    float* x2   = (float*)(ws + 66453504);   // 25,165,824
    hbf*  WoT   = (hbf*)(ws + 91619328);     //  1,179,648
    hbf*  W1T   = (hbf*)(ws + 92798976);     //  4,718,592
    hbf*  W2T   = (hbf*)(ws + 97517568);     //  4,718,592  (total 102,236,160)

    const float SCALE = 0.036084391824351615f;  // 768^-0.5

    pack_qkv_kernel<<<6912, 256, 0, stream>>>(Wq, Wk, Wv, WqkvT);
    transpose_cast_kernel<<<2304, 256, 0, stream>>>(Wo, WoT, 768, 768);
    transpose_cast_kernel<<<9216, 256, 0, stream>>>(W1, W1T, 768, 3072);
    transpose_cast_kernel<<<9216, 256, 0, stream>>>(W2, W2T, 3072, 768);
    ln_kernel<<<8192, 256, 0, stream>>>(x, ln1g, ln1b, xn);
    gemm_kernel<3><<<dim3(18, 64), 256, 0, stream>>>(xn, WqkvT, nullptr, nullptr, nullptr, nullptr,
        8192, 2304, 768, qb, kb, vb, SCALE);
    attn_kernel<<<dim3(16, 48), 256, 0, stream>>>(qb, kb, vb, attnB);
    gemm_kernel<1><<<dim3(6, 64), 256, 0, stream>>>(attnB, WoT, x2, nullptr, bo, x,
        8192, 768, 768, nullptr, nullptr, nullptr, 1.0f);
    ln_kernel<<<8192, 256, 0, stream>>>(x2, ln2g, ln2b, yln);
    gemm_kernel<2><<<dim3(24, 64), 256, 0, stream>>>(yln, W1T, nullptr, h1, b1, nullptr,
        8192, 3072, 768, nullptr, nullptr, nullptr, 1.0f);
    gemm_kernel<1><<<dim3(6, 64), 256, 0, stream>>>(h1, W2T, out, nullptr, b2, x2,
        8192, 768, 3072, nullptr, nullptr, nullptr, 1.0f);
}

// Round 3
// 416.219 us; speedup vs baseline: 1.1186x; 1.1186x over previous
//
#include <hip/hip_runtime.h>
#include <hip/hip_bf16.h>
#include <cstdint>

#define B_ 4
#define T_ 2048
#define C_ 768
#define H_ 12
#define D_ 64
#define MLP_ 3072
#define BT_ (B_*T_)

typedef __hip_bfloat16 hbf;
typedef __bf16 bf16_t;
typedef bf16_t bf16x8 __attribute__((ext_vector_type(8)));
typedef float f32x4 __attribute__((ext_vector_type(4)));

static __device__ __forceinline__ void load_lds16(const void* g, void* l) {
    __builtin_amdgcn_global_load_lds(
        (const __attribute__((address_space(1))) unsigned int*)g,
        (__attribute__((address_space(3))) unsigned int*)l, 16, 0, 0);
}

// ---------------- weight packing ----------------
__global__ __launch_bounds__(256) void pack_qkv_kernel(
    const float* __restrict__ Wq, const float* __restrict__ Wk,
    const float* __restrict__ Wv, hbf* __restrict__ dst)
{
    int idx = blockIdx.x * 256 + threadIdx.x;
    int c = idx % C_;
    int n = idx / C_;
    int t = n / C_;
    int r = n - t * C_;
    int h = r >> 6, d = r & 63;
    const float* W = (t == 0) ? Wq : (t == 1) ? Wk : Wv;
    dst[idx] = __float2bfloat16(W[((size_t)h * C_ + c) * D_ + d]);
}

__global__ __launch_bounds__(256) void transpose_cast_kernel(
    const float* __restrict__ src, hbf* __restrict__ dst, int R, int S)
{
    int idx = blockIdx.x * 256 + threadIdx.x;
    if (idx >= R * S) return;
    int r = idx % R;
    int s = idx / R;
    dst[idx] = __float2bfloat16(src[(size_t)r * S + s]);
}

// ---------------- layernorm (row = 768) ----------------
__global__ __launch_bounds__(256) void ln_kernel(
    const float* __restrict__ x, const float* __restrict__ g,
    const float* __restrict__ bb, hbf* __restrict__ out)
{
    __shared__ float red[8];
    const int row = blockIdx.x;
    const float* xr = x + (size_t)row * C_;
    const int t = threadIdx.x;
    float v0 = xr[t], v1 = xr[t + 256], v2 = xr[t + 512];
    float s = v0 + v1 + v2;
    float s2 = v0 * v0 + v1 * v1 + v2 * v2;
#pragma unroll
    for (int m = 1; m < 64; m <<= 1) {
        s  += __shfl_xor(s,  m, 64);
        s2 += __shfl_xor(s2, m, 64);
    }
    if ((t & 63) == 0) { red[t >> 6] = s; red[4 + (t >> 6)] = s2; }
    __syncthreads();
    float S  = red[0] + red[1] + red[2] + red[3];
    float S2 = red[4] + red[5] + red[6] + red[7];
    float mu  = S * (1.0f / C_);
    float var = S2 * (1.0f / C_) - mu * mu;
    float inv = rsqrtf(var + 1e-6f);
    hbf* orow = out + (size_t)row * C_;
    orow[t]       = __float2bfloat16((v0 - mu) * inv * g[t]       + bb[t]);
    orow[t + 256] = __float2bfloat16((v1 - mu) * inv * g[t + 256] + bb[t + 256]);
    orow[t + 512] = __float2bfloat16((v2 - mu) * inv * g[t + 512] + bb[t + 512]);
}

// ---------------- GEMM: C[M,N] = A[M,K](bf16) * Bt[N,K](bf16)^T ----------------
// BK=64, 128x128 tile, XOR-swizzled LDS (linear dest + pre-swizzled source).
// EPI 0: bf16 out plain
// EPI 1: f32 out = acc + bias[col] + resid[row*N+col]
// EPI 2: bf16 out = gelu(acc + bias[col])
// EPI 3: QKV scatter (N=2304)
template<int EPI>
__global__ __launch_bounds__(256, 2) void gemm_kernel(
    const hbf* __restrict__ A, const hbf* __restrict__ Bt,
    float* __restrict__ outF, hbf* __restrict__ outH,
    const float* __restrict__ bias, const float* __restrict__ resid,
    int M, int N, int K,
    hbf* __restrict__ qb, hbf* __restrict__ kb, hbf* __restrict__ vb,
    float scale)
{
    __shared__ hbf sA[128 * 64];   // 16 KB, rows of 128 B, swizzled
    __shared__ hbf sB[128 * 64];
    const int tid = threadIdx.x;
    const int lane = tid & 63;
    const int wid = tid >> 6;
    const int wm = wid >> 1, wn = wid & 1;
    const int lr = lane & 15, hg = lane >> 4;
    const int row0 = blockIdx.y * 128;
    const int col0 = blockIdx.x * 128;

    f32x4 acc[4][4] = {};

    // staging: tile = 1024 chunks of 16B; thread t handles chunks t + i*256.
    // chunk c -> LDS linear pos c*16; row = c>>3, slot = c&7.
    // source column pre-swizzled: (slot ^ (row&7))*16
    int srow[4], soff[4];
#pragma unroll
    for (int i = 0; i < 4; ++i) {
        int c = tid + i * 256;
        srow[i] = c >> 3;
        soff[i] = (((c & 7) ^ ((c >> 3) & 7)) << 4);
    }
    const char* gA = (const char*)(A + (size_t)row0 * K);
    const char* gB = (const char*)(Bt + (size_t)col0 * K);
    const int Kb = K * 2;

    for (int k0 = 0; k0 < K; k0 += 64) {
        const int kb2 = k0 * 2;
#pragma unroll
        for (int i = 0; i < 4; ++i) {
            load_lds16(gA + (size_t)srow[i] * Kb + kb2 + soff[i], (char*)sA + i * 4096 + wid * 1024);
            load_lds16(gB + (size_t)srow[i] * Kb + kb2 + soff[i], (char*)sB + i * 4096 + wid * 1024);
        }
        __syncthreads();

#pragma unroll
        for (int kf = 0; kf < 2; ++kf) {
            const int sl = ((kf * 4 + hg) ^ (lr & 7)) << 4;
            bf16x8 af[4], bfr[4];
#pragma unroll
            for (int m = 0; m < 4; ++m)
                af[m] = *(const bf16x8*)((const char*)sA + (wm * 64 + m * 16 + lr) * 128 + sl);
#pragma unroll
            for (int n = 0; n < 4; ++n)
                bfr[n] = *(const bf16x8*)((const char*)sB + (wn * 64 + n * 16 + lr) * 128 + sl);
#pragma unroll
            for (int m = 0; m < 4; ++m)
#pragma unroll
                for (int n = 0; n < 4; ++n)
                    acc[m][n] = __builtin_amdgcn_mfma_f32_16x16x32_bf16(af[m], bfr[n], acc[m][n], 0, 0, 0);
        }
        __syncthreads();
    }

#pragma unroll
    for (int m = 0; m < 4; ++m) {
#pragma unroll
        for (int n = 0; n < 4; ++n) {
#pragma unroll
            for (int j = 0; j < 4; ++j) {
                int row = row0 + wm * 64 + m * 16 + hg * 4 + j;
                int col = col0 + wn * 64 + n * 16 + lr;
                float v = acc[m][n][j];
                if constexpr (EPI == 0) {
                    outH[(size_t)row * N + col] = __float2bfloat16(v);
                } else if constexpr (EPI == 1) {
                    outF[(size_t)row * N + col] = v + bias[col] + resid[(size_t)row * N + col];
                } else if constexpr (EPI == 2) {
                    float tt = v + bias[col];
                    float ge = 0.5f * tt * (1.0f + erff(tt * 0.70710678118654752f));
                    outH[(size_t)row * N + col] = __float2bfloat16(ge);
                } else {
                    int typ = col / C_;
                    int rr = col - typ * C_;
                    int h = rr >> 6, d = rr & 63;
                    int b = row >> 11, t = row & (T_ - 1);
                    size_t bh = (size_t)b * H_ + h;
                    if (typ == 0)      qb[(bh * T_ + t) * D_ + d] = __float2bfloat16(v * scale);
                    else if (typ == 1) kb[(bh * T_ + t) * D_ + d] = __float2bfloat16(v);
                    else               vb[(bh * D_ + d) * T_ + t] = __float2bfloat16(v);
                }
            }
        }
    }
}

// ---------------- flash attention ----------------
// grid (T/128, B*H); 4 waves x 32 q-rows. q pre-scaled. vT is [bh][d][t].
// K/V double-buffered + XOR-swizzled LDS; P swizzled element-wise.
__global__ __launch_bounds__(256, 2) void attn_kernel(
    const hbf* __restrict__ qg, const hbf* __restrict__ kg,
    const hbf* __restrict__ vg, hbf* __restrict__ outA)
{
    __shared__ hbf sK[2][64 * 64];    // [s][d], swizzled, 8 KB each
    __shared__ hbf sV[2][64 * 64];    // [d][s], swizzled
    __shared__ hbf sP[4 * 32 * 64];   // per wave [r][s], swizzled
    const int tid = threadIdx.x, lane = tid & 63, wid = tid >> 6;
    const int lr = lane & 15, hg = lane >> 4;
    const int bh = blockIdx.y;
    const int b = bh / H_, h = bh - b * H_;
    const int wr0 = blockIdx.x * 128 + wid * 32;
    const hbf* qbh = qg + (size_t)bh * T_ * D_;
    const hbf* kbh = kg + (size_t)bh * T_ * D_;
    const hbf* vbh = vg + (size_t)bh * D_ * T_;

    bf16x8 a_q[2][2];
#pragma unroll
    for (int m = 0; m < 2; ++m)
#pragma unroll
        for (int kf = 0; kf < 2; ++kf)
            a_q[m][kf] = *(const bf16x8*)(qbh + (size_t)(wr0 + m * 16 + lr) * D_ + kf * 32 + hg * 8);

    f32x4 o[2][4] = {};
    float mrun[2][4], lrun[2][4];
#pragma unroll
    for (int m = 0; m < 2; ++m)
#pragma unroll
        for (int j = 0; j < 4; ++j) { mrun[m][j] = -1e30f; lrun[m][j] = 0.0f; }

    // staging geometry: K/V tile = 512 chunks of 16B; thread handles c = tid + i*256, i=0,1
    int srow[2], soff[2];
#pragma unroll
    for (int i = 0; i < 2; ++i) {
        int c = tid + i * 256;
        srow[i] = c >> 3;
        soff[i] = (((c & 7) ^ ((c >> 3) & 7)) << 4);
    }
    hbf* sPw = sP + wid * (32 * 64);

    // prologue: stage tile 0 into buf 0
#pragma unroll
    for (int i = 0; i < 2; ++i) {
        load_lds16((const char*)kbh + (size_t)srow[i] * 128 + soff[i],
                   (char*)sK[0] + i * 4096 + wid * 1024);
        load_lds16((const char*)vbh + (size_t)srow[i] * 4096 + soff[i],
                   (char*)sV[0] + i * 4096 + wid * 1024);
    }
    __syncthreads();

    for (int it = 0; it < T_ / 64; ++it) {
        const int cur = it & 1;
        // issue next tile's loads (into the buffer last read 2 barriers ago)
        if (it + 1 < T_ / 64) {
            const size_t s1 = (size_t)(it + 1) * 64;
#pragma unroll
            for (int i = 0; i < 2; ++i) {
                load_lds16((const char*)kbh + (s1 + srow[i]) * 128 + soff[i],
                           (char*)sK[cur ^ 1] + i * 4096 + wid * 1024);
                load_lds16((const char*)vbh + (size_t)srow[i] * 4096 + s1 * 2 + soff[i],
                           (char*)sV[cur ^ 1] + i * 4096 + wid * 1024);
            }
        }

        // QK^T
        f32x4 sacc[2][4] = {};
#pragma unroll
        for (int n = 0; n < 4; ++n) {
#pragma unroll
            for (int kf = 0; kf < 2; ++kf) {
                const int sl = ((kf * 4 + hg) ^ (lr & 7)) << 4;
                bf16x8 bk = *(const bf16x8*)((const char*)sK[cur] + (n * 16 + lr) * 128 + sl);
#pragma unroll
                for (int m = 0; m < 2; ++m)
                    sacc[m][n] = __builtin_amdgcn_mfma_f32_16x16x32_bf16(a_q[m][kf], bk, sacc[m][n], 0, 0, 0);
            }
        }
        // online softmax
        float fac[2][4];
#pragma unroll
        for (int m = 0; m < 2; ++m) {
#pragma unroll
            for (int j = 0; j < 4; ++j) {
                float t = fmaxf(fmaxf(sacc[m][0][j], sacc[m][1][j]),
                                fmaxf(sacc[m][2][j], sacc[m][3][j]));
                t = fmaxf(t, __shfl_xor(t, 1, 64));
                t = fmaxf(t, __shfl_xor(t, 2, 64));
                t = fmaxf(t, __shfl_xor(t, 4, 64));
                t = fmaxf(t, __shfl_xor(t, 8, 64));
                float nm = fmaxf(mrun[m][j], t);
                fac[m][j] = __expf(mrun[m][j] - nm);
                mrun[m][j] = nm;
            }
        }
        float psum[2][4] = {};
#pragma unroll
        for (int m = 0; m < 2; ++m)
#pragma unroll
            for (int n = 0; n < 4; ++n)
#pragma unroll
                for (int j = 0; j < 4; ++j) {
                    float p = __expf(sacc[m][n][j] - mrun[m][j]);
                    psum[m][j] += p;
                    int prow = m * 16 + hg * 4 + j;
                    sPw[prow * 64 + ((n * 16 + lr) ^ ((prow & 7) << 3))] = __float2bfloat16(p);
                }
#pragma unroll
        for (int m = 0; m < 2; ++m)
#pragma unroll
            for (int j = 0; j < 4; ++j) {
                float s = psum[m][j];
                s += __shfl_xor(s, 1, 64);
                s += __shfl_xor(s, 2, 64);
                s += __shfl_xor(s, 4, 64);
                s += __shfl_xor(s, 8, 64);
                lrun[m][j] = lrun[m][j] * fac[m][j] + s;
#pragma unroll
                for (int nd = 0; nd < 4; ++nd)
                    o[m][nd][j] *= fac[m][j];
            }
        __syncthreads();   // P visible (also drains staged loads into buf^1)
        // PV
#pragma unroll
        for (int kf = 0; kf < 2; ++kf) {
            const int sl = ((kf * 4 + hg) ^ (lr & 7)) << 4;
            bf16x8 ap[2];
#pragma unroll
            for (int m = 0; m < 2; ++m)
                ap[m] = *(const bf16x8*)((const char*)sPw + (m * 16 + lr) * 128 + sl);
#pragma unroll
            for (int nd = 0; nd < 4; ++nd) {
                bf16x8 bv = *(const bf16x8*)((const char*)sV[cur] + (nd * 16 + lr) * 128 + sl);
#pragma unroll
                for (int m = 0; m < 2; ++m)
                    o[m][nd] = __builtin_amdgcn_mfma_f32_16x16x32_bf16(ap[m], bv, o[m][nd], 0, 0, 0);
            }
        }
        __syncthreads();   // all waves done reading cur + sP before next overwrite
    }

#pragma unroll
    for (int m = 0; m < 2; ++m)
#pragma unroll
        for (int nd = 0; nd < 4; ++nd)
#pragma unroll
            for (int j = 0; j < 4; ++j) {
                int row = wr0 + m * 16 + hg * 4 + j;
                int col = nd * 16 + lr;
                float val = o[m][nd][j] / lrun[m][j];
                outA[((size_t)(b * T_ + row)) * C_ + h * D_ + col] = __float2bfloat16(val);
            }
}

// ---------------- launch ----------------
extern "C" void kernel_launch(void* const* d_in, const int* in_sizes, int n_in,
                              void* d_out, int out_size, void* d_ws, size_t ws_size,
                              hipStream_t stream)
{
    const float* x    = (const float*)d_in[0];
    const float* Wq   = (const float*)d_in[1];
    const float* Wk   = (const float*)d_in[2];
    const float* Wv   = (const float*)d_in[3];
    const float* Wo   = (const float*)d_in[4];
    const float* bo   = (const float*)d_in[5];
    const float* ln1g = (const float*)d_in[6];
    const float* ln1b = (const float*)d_in[7];
    const float* ln2g = (const float*)d_in[8];
    const float* ln2b = (const float*)d_in[9];
    const float* W1   = (const float*)d_in[10];
    const float* b1   = (const float*)d_in[11];
    const float* W2   = (const float*)d_in[12];
    const float* b2   = (const float*)d_in[13];
    float* out = (float*)d_out;
    char* ws = (char*)d_ws;

    hbf*  xn    = (hbf*)(ws + 0);
    hbf*  WqkvT = (hbf*)(ws + 12582912);
    hbf*  qb    = (hbf*)(ws + 16121856);
    hbf*  kb    = (hbf*)(ws + 28704768);
    hbf*  vb    = (hbf*)(ws + 41287680);
    hbf*  h1    = (hbf*)(ws + 0);
    hbf*  attnB = (hbf*)(ws + 53870592);
    hbf*  yln   = (hbf*)(ws + 53870592);
    float* x2   = (float*)(ws + 66453504);
    hbf*  WoT   = (hbf*)(ws + 91619328);
    hbf*  W1T   = (hbf*)(ws + 92798976);
    hbf*  W2T   = (hbf*)(ws + 97517568);

    const float SCALE = 0.036084391824351615f;  // 768^-0.5

    pack_qkv_kernel<<<6912, 256, 0, stream>>>(Wq, Wk, Wv, WqkvT);
    transpose_cast_kernel<<<2304, 256, 0, stream>>>(Wo, WoT, 768, 768);
    transpose_cast_kernel<<<9216, 256, 0, stream>>>(W1, W1T, 768, 3072);
    transpose_cast_kernel<<<9216, 256, 0, stream>>>(W2, W2T, 3072, 768);
    ln_kernel<<<8192, 256, 0, stream>>>(x, ln1g, ln1b, xn);
    gemm_kernel<3><<<dim3(18, 64), 256, 0, stream>>>(xn, WqkvT, nullptr, nullptr, nullptr, nullptr,
        8192, 2304, 768, qb, kb, vb, SCALE);
    attn_kernel<<<dim3(16, 48), 256, 0, stream>>>(qb, kb, vb, attnB);
    gemm_kernel<1><<<dim3(6, 64), 256, 0, stream>>>(attnB, WoT, x2, nullptr, bo, x,
        8192, 768, 768, nullptr, nullptr, nullptr, 1.0f);
    ln_kernel<<<8192, 256, 0, stream>>>(x2, ln2g, ln2b, yln);
    gemm_kernel<2><<<dim3(24, 64), 256, 0, stream>>>(yln, W1T, nullptr, h1, b1, nullptr,
        8192, 3072, 768, nullptr, nullptr, nullptr, 1.0f);
    gemm_kernel<1><<<dim3(6, 64), 256, 0, stream>>>(h1, W2T, out, nullptr, b2, x2,
        8192, 768, 3072, nullptr, nullptr, nullptr, 1.0f);
}

// Round 4
// 345.013 us; speedup vs baseline: 1.3495x; 1.2064x over previous
//
#include <hip/hip_runtime.h>
#include <hip/hip_bf16.h>
#include <cstdint>

#define B_ 4
#define T_ 2048
#define C_ 768
#define H_ 12
#define D_ 64
#define MLP_ 3072
#define BT_ (B_*T_)

typedef __hip_bfloat16 hbf;
typedef __bf16 bf16_t;
typedef bf16_t bf16x8 __attribute__((ext_vector_type(8)));
typedef bf16_t bf16x4 __attribute__((ext_vector_type(4)));
typedef float f32x4 __attribute__((ext_vector_type(4)));

static __device__ __forceinline__ void load_lds16(const void* g, void* l) {
    __builtin_amdgcn_global_load_lds(
        (const __attribute__((address_space(1))) unsigned int*)g,
        (__attribute__((address_space(3))) unsigned int*)l, 16, 0, 0);
}

// ---------------- weight packing ----------------
__global__ __launch_bounds__(256) void pack_qkv_kernel(
    const float* __restrict__ Wq, const float* __restrict__ Wk,
    const float* __restrict__ Wv, hbf* __restrict__ dst)
{
    int idx = blockIdx.x * 256 + threadIdx.x;
    int c = idx % C_;
    int n = idx / C_;
    int t = n / C_;
    int r = n - t * C_;
    int h = r >> 6, d = r & 63;
    const float* W = (t == 0) ? Wq : (t == 1) ? Wk : Wv;
    dst[idx] = __float2bfloat16(W[((size_t)h * C_ + c) * D_ + d]);
}

__global__ __launch_bounds__(256) void transpose_cast_kernel(
    const float* __restrict__ src, hbf* __restrict__ dst, int R, int S)
{
    int idx = blockIdx.x * 256 + threadIdx.x;
    if (idx >= R * S) return;
    int r = idx % R;
    int s = idx / R;
    dst[idx] = __float2bfloat16(src[(size_t)r * S + s]);
}

// ---------------- layernorm (row = 768) ----------------
__global__ __launch_bounds__(256) void ln_kernel(
    const float* __restrict__ x, const float* __restrict__ g,
    const float* __restrict__ bb, hbf* __restrict__ out)
{
    __shared__ float red[8];
    const int row = blockIdx.x;
    const float* xr = x + (size_t)row * C_;
    const int t = threadIdx.x;
    float v0 = xr[t], v1 = xr[t + 256], v2 = xr[t + 512];
    float s = v0 + v1 + v2;
    float s2 = v0 * v0 + v1 * v1 + v2 * v2;
#pragma unroll
    for (int m = 1; m < 64; m <<= 1) {
        s  += __shfl_xor(s,  m, 64);
        s2 += __shfl_xor(s2, m, 64);
    }
    if ((t & 63) == 0) { red[t >> 6] = s; red[4 + (t >> 6)] = s2; }
    __syncthreads();
    float S  = red[0] + red[1] + red[2] + red[3];
    float S2 = red[4] + red[5] + red[6] + red[7];
    float mu  = S * (1.0f / C_);
    float var = S2 * (1.0f / C_) - mu * mu;
    float inv = rsqrtf(var + 1e-6f);
    hbf* orow = out + (size_t)row * C_;
    orow[t]       = __float2bfloat16((v0 - mu) * inv * g[t]       + bb[t]);
    orow[t + 256] = __float2bfloat16((v1 - mu) * inv * g[t + 256] + bb[t + 256]);
    orow[t + 512] = __float2bfloat16((v2 - mu) * inv * g[t + 512] + bb[t + 512]);
}

// ---------------- GEMM: C[M,N] = A[M,K](bf16) * Bt[N,K](bf16)^T ----------------
// BK=64, 128x128 tile, XOR-swizzled LDS, 2-phase double-buffer (stage issued
// before compute, one barrier per K-step; static buffers so no false aliasing).
template<int EPI>
__global__ __launch_bounds__(256, 2) void gemm_kernel(
    const hbf* __restrict__ A, const hbf* __restrict__ Bt,
    float* __restrict__ outF, hbf* __restrict__ outH,
    const float* __restrict__ bias, const float* __restrict__ resid,
    int M, int N, int K,
    hbf* __restrict__ qb, hbf* __restrict__ kb, hbf* __restrict__ vb,
    float scale)
{
    __shared__ hbf sA0[128 * 64], sA1[128 * 64];   // 16 KB each
    __shared__ hbf sB0[128 * 64], sB1[128 * 64];
    const int tid = threadIdx.x;
    const int lane = tid & 63;
    const int wid = tid >> 6;
    const int wm = wid >> 1, wn = wid & 1;
    const int lr = lane & 15, hg = lane >> 4;
    const int row0 = blockIdx.y * 128;
    const int col0 = blockIdx.x * 128;

    f32x4 acc[4][4] = {};

    // chunk c = tid + i*256 -> LDS linear c*16; row=c>>3, slot=c&7, source col pre-swizzled
    int offG[4];
    const int Kb = K * 2;
#pragma unroll
    for (int i = 0; i < 4; ++i) {
        int c = tid + i * 256;
        offG[i] = (c >> 3) * Kb + (((c & 7) ^ ((c >> 3) & 7)) << 4);
    }
    const char* gA = (const char*)(A + (size_t)row0 * K);
    const char* gB = (const char*)(Bt + (size_t)col0 * K);

    auto stage = [&](int kt, hbf* sAd, hbf* sBd) {
        const int kb2 = kt * 128;   // kt*64 elements * 2 bytes
#pragma unroll
        for (int i = 0; i < 4; ++i) {
            load_lds16(gA + (size_t)(offG[i] + kb2), (char*)sAd + i * 4096 + wid * 1024);
            load_lds16(gB + (size_t)(offG[i] + kb2), (char*)sBd + i * 4096 + wid * 1024);
        }
    };
    auto compute = [&](const hbf* sAc, const hbf* sBc) {
#pragma unroll
        for (int kf = 0; kf < 2; ++kf) {
            const int sl = ((kf * 4 + hg) ^ (lr & 7)) << 4;
            bf16x8 af[4], bfr[4];
#pragma unroll
            for (int m = 0; m < 4; ++m)
                af[m] = *(const bf16x8*)((const char*)sAc + (wm * 64 + m * 16 + lr) * 128 + sl);
#pragma unroll
            for (int n = 0; n < 4; ++n)
                bfr[n] = *(const bf16x8*)((const char*)sBc + (wn * 64 + n * 16 + lr) * 128 + sl);
#pragma unroll
            for (int m = 0; m < 4; ++m)
#pragma unroll
                for (int n = 0; n < 4; ++n)
                    acc[m][n] = __builtin_amdgcn_mfma_f32_16x16x32_bf16(af[m], bfr[n], acc[m][n], 0, 0, 0);
        }
    };

    const int NK = K >> 6;          // 12 or 48, always even
    stage(0, sA0, sB0);
    __syncthreads();
    for (int kt = 0; kt < NK; kt += 2) {
        stage(kt + 1, sA1, sB1);    // kt+1 < NK always (NK even)
        compute(sA0, sB0);
        __syncthreads();
        if (kt + 2 < NK) stage(kt + 2, sA0, sB0);
        compute(sA1, sB1);
        __syncthreads();
    }

#pragma unroll
    for (int m = 0; m < 4; ++m) {
#pragma unroll
        for (int n = 0; n < 4; ++n) {
#pragma unroll
            for (int j = 0; j < 4; ++j) {
                int row = row0 + wm * 64 + m * 16 + hg * 4 + j;
                int col = col0 + wn * 64 + n * 16 + lr;
                float v = acc[m][n][j];
                if constexpr (EPI == 0) {
                    outH[(size_t)row * N + col] = __float2bfloat16(v);
                } else if constexpr (EPI == 1) {
                    outF[(size_t)row * N + col] = v + bias[col] + resid[(size_t)row * N + col];
                } else if constexpr (EPI == 2) {
                    float tt = v + bias[col];
                    float ge = 0.5f * tt * (1.0f + erff(tt * 0.70710678118654752f));
                    outH[(size_t)row * N + col] = __float2bfloat16(ge);
                } else {
                    int typ = col / C_;
                    int rr = col - typ * C_;
                    int h = rr >> 6, d = rr & 63;
                    int b = row >> 11, t = row & (T_ - 1);
                    size_t bh = (size_t)b * H_ + h;
                    if (typ == 0)      qb[(bh * T_ + t) * D_ + d] = __float2bfloat16(v * scale);
                    else if (typ == 1) kb[(bh * T_ + t) * D_ + d] = __float2bfloat16(v);
                    else               vb[(bh * D_ + d) * T_ + t] = __float2bfloat16(v);
                }
            }
        }
    }
}

// ---------------- flash attention (swapped QK^T, defer-max) ----------------
// grid (T/128, B*H); 4 waves x 32 q-rows. q pre-scaled. vT is [bh][d][t].
// S^T = mfma(K,Q): lane owns q-row (lane&15) per m-block -> lane-local softmax.
__global__ __launch_bounds__(256, 2) void attn_kernel(
    const hbf* __restrict__ qg, const hbf* __restrict__ kg,
    const hbf* __restrict__ vg, hbf* __restrict__ outA)
{
    __shared__ hbf sK0[64 * 64], sK1[64 * 64];   // [s][d], swizzled
    __shared__ hbf sV0[64 * 64], sV1[64 * 64];   // [d][s], swizzled
    __shared__ hbf sP[4 * 32 * 64];              // per wave [q=32][kv=64], swizzled
    const int tid = threadIdx.x, lane = tid & 63, wid = tid >> 6;
    const int lr = lane & 15, hg = lane >> 4;
    const int bh = blockIdx.y;
    const int b = bh / H_, h = bh - b * H_;
    const int wr0 = blockIdx.x * 128 + wid * 32;
    const hbf* qbh = qg + (size_t)bh * T_ * D_;
    const hbf* kbh = kg + (size_t)bh * T_ * D_;
    const hbf* vbh = vg + (size_t)bh * D_ * T_;

    bf16x8 a_q[2][2];
#pragma unroll
    for (int m = 0; m < 2; ++m)
#pragma unroll
        for (int kf = 0; kf < 2; ++kf)
            a_q[m][kf] = *(const bf16x8*)(qbh + (size_t)(wr0 + m * 16 + lr) * D_ + kf * 32 + hg * 8);

    f32x4 o[2][4] = {};
    float mreg[2] = {-3e38f, -3e38f};
    float lrun[2] = {0.0f, 0.0f};

    // staging offsets (chunk c = tid + i*256)
    int offK[2], offV[2];
#pragma unroll
    for (int i = 0; i < 2; ++i) {
        int c = tid + i * 256;
        int sw = ((c & 7) ^ ((c >> 3) & 7)) << 4;
        offK[i] = (c >> 3) * 128 + sw;
        offV[i] = (c >> 3) * 4096 + sw;
    }
    hbf* sPw = sP + wid * (32 * 64);
    const int sl0 = ((0 * 4 + hg) ^ (lr & 7)) << 4;
    const int sl1 = ((1 * 4 + hg) ^ (lr & 7)) << 4;
    const int bcast = hg * 20;   // source lane base: hg*16 + hg*4

    auto stage = [&](int itn, hbf* sKd, hbf* sVd) {
        const char* kp = (const char*)kbh + (size_t)itn * 8192;
        const char* vp = (const char*)vbh + (size_t)itn * 128;
#pragma unroll
        for (int i = 0; i < 2; ++i) {
            load_lds16(kp + offK[i], (char*)sKd + i * 4096 + wid * 1024);
            load_lds16(vp + offV[i], (char*)sVd + i * 4096 + wid * 1024);
        }
    };

    auto tile = [&](const hbf* sKc, const hbf* sVc) {
        // swapped QK^T: st[n][m] has kv-row = n*16+hg*4+j, q-col = m*16+lr
        f32x4 st[4][2] = {};
        __builtin_amdgcn_s_setprio(1);
#pragma unroll
        for (int kf = 0; kf < 2; ++kf) {
            const int sl = kf ? sl1 : sl0;
#pragma unroll
            for (int n = 0; n < 4; ++n) {
                bf16x8 ak = *(const bf16x8*)((const char*)sKc + (n * 16 + lr) * 128 + sl);
                st[n][0] = __builtin_amdgcn_mfma_f32_16x16x32_bf16(ak, a_q[0][kf], st[n][0], 0, 0, 0);
                st[n][1] = __builtin_amdgcn_mfma_f32_16x16x32_bf16(ak, a_q[1][kf], st[n][1], 0, 0, 0);
            }
        }
        __builtin_amdgcn_s_setprio(0);

        // lane-local softmax per m-block (lane owns q-row m*16+lr)
#pragma unroll
        for (int m = 0; m < 2; ++m) {
            float t = st[0][m][0];
#pragma unroll
            for (int n = 0; n < 4; ++n)
#pragma unroll
                for (int j = 0; j < 4; ++j)
                    t = fmaxf(t, st[n][m][j]);
            t = fmaxf(t, __shfl_xor(t, 16, 64));
            t = fmaxf(t, __shfl_xor(t, 32, 64));
            if (__any(t - mreg[m] > 8.0f)) {       // defer-max: rarely taken
                float nm = fmaxf(mreg[m], t);
                float fac = __expf(mreg[m] - nm);
                mreg[m] = nm;
                lrun[m] *= fac;
                float fb[4];
#pragma unroll
                for (int j = 0; j < 4; ++j)
                    fb[j] = __shfl(fac, bcast + j, 64);
#pragma unroll
                for (int nd = 0; nd < 4; ++nd)
#pragma unroll
                    for (int j = 0; j < 4; ++j)
                        o[m][nd][j] *= fb[j];
            }
            float ps = 0.0f;
            const int r = m * 16 + lr;
#pragma unroll
            for (int n = 0; n < 4; ++n) {
                float p0 = __expf(st[n][m][0] - mreg[m]);
                float p1 = __expf(st[n][m][1] - mreg[m]);
                float p2 = __expf(st[n][m][2] - mreg[m]);
                float p3 = __expf(st[n][m][3] - mreg[m]);
                ps += (p0 + p1) + (p2 + p3);
                bf16x4 w;
                w[0] = (bf16_t)p0; w[1] = (bf16_t)p1; w[2] = (bf16_t)p2; w[3] = (bf16_t)p3;
                // element (r, kv=n*16+hg*4+j): slot16 = n*2+(hg>>1), off = (hg&1)*8
                *(bf16x4*)((char*)sPw + r * 128 +
                           (((n * 2 + (hg >> 1)) ^ (r & 7)) << 4) + ((hg & 1) * 8)) = w;
            }
            ps += __shfl_xor(ps, 16, 64);
            ps += __shfl_xor(ps, 32, 64);
            lrun[m] += ps;
        }

        // PV: P is wave-private (in-order DS pipe; no block barrier needed)
        __builtin_amdgcn_s_setprio(1);
#pragma unroll
        for (int kf = 0; kf < 2; ++kf) {
            const int sl = kf ? sl1 : sl0;
            bf16x8 ap0 = *(const bf16x8*)((const char*)sPw + lr * 128 + sl);
            bf16x8 ap1 = *(const bf16x8*)((const char*)sPw + (16 + lr) * 128 + sl);
#pragma unroll
            for (int nd = 0; nd < 4; ++nd) {
                bf16x8 bv = *(const bf16x8*)((const char*)sVc + (nd * 16 + lr) * 128 + sl);
                o[0][nd] = __builtin_amdgcn_mfma_f32_16x16x32_bf16(ap0, bv, o[0][nd], 0, 0, 0);
                o[1][nd] = __builtin_amdgcn_mfma_f32_16x16x32_bf16(ap1, bv, o[1][nd], 0, 0, 0);
            }
        }
        __builtin_amdgcn_s_setprio(0);
    };

    const int NT = T_ / 64;   // 32, even
    stage(0, sK0, sV0);
    __syncthreads();
    for (int it = 0; it < NT; it += 2) {
        stage(it + 1, sK1, sV1);            // it+1 < NT always
        tile(sK0, sV0);
        __syncthreads();
        if (it + 2 < NT) stage(it + 2, sK0, sV0);
        tile(sK1, sV1);
        __syncthreads();
    }

    // epilogue: broadcast lrun (held at lane lr = q-row) to o-layout rows hg*4+j
    float lb[2][4];
#pragma unroll
    for (int m = 0; m < 2; ++m)
#pragma unroll
        for (int j = 0; j < 4; ++j)
            lb[m][j] = __shfl(lrun[m], bcast + j, 64);
#pragma unroll
    for (int m = 0; m < 2; ++m)
#pragma unroll
        for (int nd = 0; nd < 4; ++nd)
#pragma unroll
            for (int j = 0; j < 4; ++j) {
                int row = wr0 + m * 16 + hg * 4 + j;
                int col = nd * 16 + lr;
                float val = o[m][nd][j] / lb[m][j];
                outA[((size_t)(b * T_ + row)) * C_ + h * D_ + col] = __float2bfloat16(val);
            }
}

// ---------------- launch ----------------
extern "C" void kernel_launch(void* const* d_in, const int* in_sizes, int n_in,
                              void* d_out, int out_size, void* d_ws, size_t ws_size,
                              hipStream_t stream)
{
    const float* x    = (const float*)d_in[0];
    const float* Wq   = (const float*)d_in[1];
    const float* Wk   = (const float*)d_in[2];
    const float* Wv   = (const float*)d_in[3];
    const float* Wo   = (const float*)d_in[4];
    const float* bo   = (const float*)d_in[5];
    const float* ln1g = (const float*)d_in[6];
    const float* ln1b = (const float*)d_in[7];
    const float* ln2g = (const float*)d_in[8];
    const float* ln2b = (const float*)d_in[9];
    const float* W1   = (const float*)d_in[10];
    const float* b1   = (const float*)d_in[11];
    const float* W2   = (const float*)d_in[12];
    const float* b2   = (const float*)d_in[13];
    float* out = (float*)d_out;
    char* ws = (char*)d_ws;

    hbf*  xn    = (hbf*)(ws + 0);
    hbf*  WqkvT = (hbf*)(ws + 12582912);
    hbf*  qb    = (hbf*)(ws + 16121856);
    hbf*  kb    = (hbf*)(ws + 28704768);
    hbf*  vb    = (hbf*)(ws + 41287680);
    hbf*  h1    = (hbf*)(ws + 0);
    hbf*  attnB = (hbf*)(ws + 53870592);
    hbf*  yln   = (hbf*)(ws + 53870592);
    float* x2   = (float*)(ws + 66453504);
    hbf*  WoT   = (hbf*)(ws + 91619328);
    hbf*  W1T   = (hbf*)(ws + 92798976);
    hbf*  W2T   = (hbf*)(ws + 97517568);

    const float SCALE = 0.036084391824351615f;  // 768^-0.5

    pack_qkv_kernel<<<6912, 256, 0, stream>>>(Wq, Wk, Wv, WqkvT);
    transpose_cast_kernel<<<2304, 256, 0, stream>>>(Wo, WoT, 768, 768);
    transpose_cast_kernel<<<9216, 256, 0, stream>>>(W1, W1T, 768, 3072);
    transpose_cast_kernel<<<9216, 256, 0, stream>>>(W2, W2T, 3072, 768);
    ln_kernel<<<8192, 256, 0, stream>>>(x, ln1g, ln1b, xn);
    gemm_kernel<3><<<dim3(18, 64), 256, 0, stream>>>(xn, WqkvT, nullptr, nullptr, nullptr, nullptr,
        8192, 2304, 768, qb, kb, vb, SCALE);
    attn_kernel<<<dim3(16, 48), 256, 0, stream>>>(qb, kb, vb, attnB);
    gemm_kernel<1><<<dim3(6, 64), 256, 0, stream>>>(attnB, WoT, x2, nullptr, bo, x,
        8192, 768, 768, nullptr, nullptr, nullptr, 1.0f);
    ln_kernel<<<8192, 256, 0, stream>>>(x2, ln2g, ln2b, yln);
    gemm_kernel<2><<<dim3(24, 64), 256, 0, stream>>>(yln, W1T, nullptr, h1, b1, nullptr,
        8192, 3072, 768, nullptr, nullptr, nullptr, 1.0f);
    gemm_kernel<1><<<dim3(6, 64), 256, 0, stream>>>(h1, W2T, out, nullptr, b2, x2,
        8192, 768, 3072, nullptr, nullptr, nullptr, 1.0f);
}

// Round 5
// 323.763 us; speedup vs baseline: 1.4380x; 1.0656x over previous
//
#include <hip/hip_runtime.h>
#include <hip/hip_bf16.h>
#include <cstdint>
#include <cmath>

#define B_ 4
#define T_ 2048
#define C_ 768
#define H_ 12
#define D_ 64
#define MLP_ 3072
#define BT_ (B_*T_)

typedef __hip_bfloat16 hbf;
typedef __bf16 bf16_t;
typedef bf16_t bf16x8 __attribute__((ext_vector_type(8)));
typedef bf16_t bf16x4 __attribute__((ext_vector_type(4)));
typedef float f32x4 __attribute__((ext_vector_type(4)));

static __device__ __forceinline__ void load_lds16(const void* g, void* l) {
    __builtin_amdgcn_global_load_lds(
        (const __attribute__((address_space(1))) unsigned int*)g,
        (__attribute__((address_space(3))) unsigned int*)l, 16, 0, 0);
}

// ---------------- LDS-tiled transpose: f32 [R][S] -> bf16 [S][R] ----------------
// blockIdx.z advances both src and dst by R*S (per-head packing: Wq[h][c][d]
// is h independent [768][64] matrices; dst block h occupies rows h*64..h*64+63).
__global__ __launch_bounds__(256) void transpose_pack(
    const float* __restrict__ src, hbf* __restrict__ dst, int R, int S)
{
    __shared__ float tl[64 * 65];
    src += (size_t)blockIdx.z * R * S;
    dst += (size_t)blockIdx.z * R * S;
    const int r0 = blockIdx.y * 64, s0 = blockIdx.x * 64;
    const int c = threadIdx.x & 63, q = threadIdx.x >> 6;
#pragma unroll
    for (int j = 0; j < 16; ++j) {
        int r = q + j * 4;
        tl[r * 65 + c] = src[(size_t)(r0 + r) * S + s0 + c];   // 256B coalesced
    }
    __syncthreads();
#pragma unroll
    for (int j = 0; j < 16; ++j) {
        int s = q + j * 4;
        dst[(size_t)(s0 + s) * R + r0 + c] = __float2bfloat16(tl[c * 65 + s]);
    }
}

// ---------------- layernorm (row = 768) ----------------
__global__ __launch_bounds__(256) void ln_kernel(
    const float* __restrict__ x, const float* __restrict__ g,
    const float* __restrict__ bb, hbf* __restrict__ out)
{
    __shared__ float red[8];
    const int row = blockIdx.x;
    const float* xr = x + (size_t)row * C_;
    const int t = threadIdx.x;
    float v0 = xr[t], v1 = xr[t + 256], v2 = xr[t + 512];
    float s = v0 + v1 + v2;
    float s2 = v0 * v0 + v1 * v1 + v2 * v2;
#pragma unroll
    for (int m = 1; m < 64; m <<= 1) {
        s  += __shfl_xor(s,  m, 64);
        s2 += __shfl_xor(s2, m, 64);
    }
    if ((t & 63) == 0) { red[t >> 6] = s; red[4 + (t >> 6)] = s2; }
    __syncthreads();
    float S  = red[0] + red[1] + red[2] + red[3];
    float S2 = red[4] + red[5] + red[6] + red[7];
    float mu  = S * (1.0f / C_);
    float var = S2 * (1.0f / C_) - mu * mu;
    float inv = rsqrtf(var + 1e-6f);
    hbf* orow = out + (size_t)row * C_;
    orow[t]       = __float2bfloat16((v0 - mu) * inv * g[t]       + bb[t]);
    orow[t + 256] = __float2bfloat16((v1 - mu) * inv * g[t + 256] + bb[t + 256]);
    orow[t + 512] = __float2bfloat16((v2 - mu) * inv * g[t + 512] + bb[t + 512]);
}

// ---------------- GEMM: C[M,N] = A[M,K](bf16) * Bt[N,K](bf16)^T ----------------
// BK=64, 128x128 tile, XOR-swizzled LDS, 2-phase dbuf, 1D grid + XCD swizzle.
// EPI 0: bf16 out plain          EPI 1: f32 out = acc + bias + resid
// EPI 2: bf16 gelu(acc + bias)   EPI 3: q/k scatter (N=1536)
template<int EPI>
__global__ __launch_bounds__(256, 2) void gemm_kernel(
    const hbf* __restrict__ A, const hbf* __restrict__ Bt,
    float* __restrict__ outF, hbf* __restrict__ outH,
    const float* __restrict__ bias, const float* __restrict__ resid,
    int M, int N, int K,
    hbf* __restrict__ qb, hbf* __restrict__ kb,
    float scale, int gx)
{
    __shared__ hbf sA0[128 * 64], sA1[128 * 64];
    __shared__ hbf sB0[128 * 64], sB1[128 * 64];
    const int tid = threadIdx.x;
    const int lane = tid & 63;
    const int wid = tid >> 6;
    const int wm = wid >> 1, wn = wid & 1;
    const int lr = lane & 15, hg = lane >> 4;
    // XCD-aware remap: consecutive wg (same by -> shared A panel) land on one XCD
    const int bid = blockIdx.x, nwg = gridDim.x;
    const int wg = (bid & 7) * (nwg >> 3) + (bid >> 3);
    const int bx = wg % gx, by = wg / gx;
    const int row0 = by * 128;
    const int col0 = bx * 128;

    f32x4 acc[4][4] = {};

    int offG[4];
    const int Kb = K * 2;
#pragma unroll
    for (int i = 0; i < 4; ++i) {
        int c = tid + i * 256;
        offG[i] = (c >> 3) * Kb + (((c & 7) ^ ((c >> 3) & 7)) << 4);
    }
    const char* gA = (const char*)(A + (size_t)row0 * K);
    const char* gB = (const char*)(Bt + (size_t)col0 * K);

    auto stage = [&](int kt, hbf* sAd, hbf* sBd) {
        const int kb2 = kt * 128;
#pragma unroll
        for (int i = 0; i < 4; ++i) {
            load_lds16(gA + (size_t)(offG[i] + kb2), (char*)sAd + i * 4096 + wid * 1024);
            load_lds16(gB + (size_t)(offG[i] + kb2), (char*)sBd + i * 4096 + wid * 1024);
        }
    };
    auto compute = [&](const hbf* sAc, const hbf* sBc) {
#pragma unroll
        for (int kf = 0; kf < 2; ++kf) {
            const int sl = ((kf * 4 + hg) ^ (lr & 7)) << 4;
            bf16x8 af[4], bfr[4];
#pragma unroll
            for (int m = 0; m < 4; ++m)
                af[m] = *(const bf16x8*)((const char*)sAc + (wm * 64 + m * 16 + lr) * 128 + sl);
#pragma unroll
            for (int n = 0; n < 4; ++n)
                bfr[n] = *(const bf16x8*)((const char*)sBc + (wn * 64 + n * 16 + lr) * 128 + sl);
#pragma unroll
            for (int m = 0; m < 4; ++m)
#pragma unroll
                for (int n = 0; n < 4; ++n)
                    acc[m][n] = __builtin_amdgcn_mfma_f32_16x16x32_bf16(af[m], bfr[n], acc[m][n], 0, 0, 0);
        }
    };

    const int NK = K >> 6;          // 12 or 48, always even
    stage(0, sA0, sB0);
    __syncthreads();
    for (int kt = 0; kt < NK; kt += 2) {
        stage(kt + 1, sA1, sB1);
        compute(sA0, sB0);
        __syncthreads();
        if (kt + 2 < NK) stage(kt + 2, sA0, sB0);
        compute(sA1, sB1);
        __syncthreads();
    }

#pragma unroll
    for (int m = 0; m < 4; ++m) {
#pragma unroll
        for (int n = 0; n < 4; ++n) {
#pragma unroll
            for (int j = 0; j < 4; ++j) {
                int row = row0 + wm * 64 + m * 16 + hg * 4 + j;
                int col = col0 + wn * 64 + n * 16 + lr;
                float v = acc[m][n][j];
                if constexpr (EPI == 0) {
                    outH[(size_t)row * N + col] = __float2bfloat16(v);
                } else if constexpr (EPI == 1) {
                    outF[(size_t)row * N + col] = v + bias[col] + resid[(size_t)row * N + col];
                } else if constexpr (EPI == 2) {
                    float tt = v + bias[col];
                    float ge = 0.5f * tt * (1.0f + erff(tt * 0.70710678118654752f));
                    outH[(size_t)row * N + col] = __float2bfloat16(ge);
                } else {
                    int typ = col / C_;            // 0=q, 1=k
                    int rr = col - typ * C_;
                    int h = rr >> 6, d = rr & 63;
                    int b = row >> 11, t = row & (T_ - 1);
                    size_t bh = (size_t)b * H_ + h;
                    if (typ == 0) qb[(bh * T_ + t) * D_ + d] = __float2bfloat16(v * scale);
                    else          kb[(bh * T_ + t) * D_ + d] = __float2bfloat16(v);
                }
            }
        }
    }
}

// ---------------- flash attention (swapped QK^T, defer-max, exp2 domain) -------
// 1D grid 768 (XCD-swizzled, bh-major). 4 waves x 32 q-rows. q pre-scaled by
// 768^-0.5 * log2(e)  ->  softmax entirely in exp2. vT is [hd=768][B*T=8192].
__global__ __launch_bounds__(256, 2) void attn_kernel(
    const hbf* __restrict__ qg, const hbf* __restrict__ kg,
    const hbf* __restrict__ vg, hbf* __restrict__ outA)
{
    __shared__ hbf sK0[64 * 64], sK1[64 * 64];   // [s][d], swizzled
    __shared__ hbf sV0[64 * 64], sV1[64 * 64];   // [d][s], swizzled
    __shared__ hbf sP[4 * 32 * 64];              // per wave [q=32][kv=64], swizzled
    const int tid = threadIdx.x, lane = tid & 63, wid = tid >> 6;
    const int lr = lane & 15, hg = lane >> 4;
    const int wg = (blockIdx.x & 7) * 96 + (blockIdx.x >> 3);   // 768/8 = 96
    const int bh = wg >> 4;
    const int b = bh / H_, h = bh - b * H_;
    const int wr0 = (wg & 15) * 128 + wid * 32;
    const hbf* qbh = qg + (size_t)bh * T_ * D_;
    const hbf* kbh = kg + (size_t)bh * T_ * D_;
    const hbf* vbh = vg + (size_t)h * 64 * BT_ + (size_t)b * T_;   // row d: +d*8192

    bf16x8 a_q[2][2];
#pragma unroll
    for (int m = 0; m < 2; ++m)
#pragma unroll
        for (int kf = 0; kf < 2; ++kf)
            a_q[m][kf] = *(const bf16x8*)(qbh + (size_t)(wr0 + m * 16 + lr) * D_ + kf * 32 + hg * 8);

    f32x4 o[2][4] = {};
    float mreg[2] = {-3e38f, -3e38f};
    float lrun[2] = {0.0f, 0.0f};

    int offK[2], offV[2];
#pragma unroll
    for (int i = 0; i < 2; ++i) {
        int c = tid + i * 256;
        int sw = ((c & 7) ^ ((c >> 3) & 7)) << 4;
        offK[i] = (c >> 3) * 128 + sw;
        offV[i] = (c >> 3) * (BT_ * 2) + sw;
    }
    hbf* sPw = sP + wid * (32 * 64);
    const int sl0 = ((0 * 4 + hg) ^ (lr & 7)) << 4;
    const int sl1 = ((1 * 4 + hg) ^ (lr & 7)) << 4;
    const int bcast = hg * 20;

    auto stage = [&](int itn, hbf* sKd, hbf* sVd) {
        const char* kp = (const char*)kbh + (size_t)itn * 8192;
        const char* vp = (const char*)vbh + (size_t)itn * 128;
#pragma unroll
        for (int i = 0; i < 2; ++i) {
            load_lds16(kp + offK[i], (char*)sKd + i * 4096 + wid * 1024);
            load_lds16(vp + offV[i], (char*)sVd + i * 4096 + wid * 1024);
        }
    };

    auto tile = [&](const hbf* sKc, const hbf* sVc) {
        f32x4 st[4][2] = {};
        __builtin_amdgcn_s_setprio(1);
#pragma unroll
        for (int kf = 0; kf < 2; ++kf) {
            const int sl = kf ? sl1 : sl0;
#pragma unroll
            for (int n = 0; n < 4; ++n) {
                bf16x8 ak = *(const bf16x8*)((const char*)sKc + (n * 16 + lr) * 128 + sl);
                st[n][0] = __builtin_amdgcn_mfma_f32_16x16x32_bf16(ak, a_q[0][kf], st[n][0], 0, 0, 0);
                st[n][1] = __builtin_amdgcn_mfma_f32_16x16x32_bf16(ak, a_q[1][kf], st[n][1], 0, 0, 0);
            }
        }
        __builtin_amdgcn_s_setprio(0);

#pragma unroll
        for (int m = 0; m < 2; ++m) {
            float t = fmaxf(fmaxf(st[0][m][0], st[0][m][1]), fmaxf(st[0][m][2], st[0][m][3]));
#pragma unroll
            for (int n = 1; n < 4; ++n)
                t = fmaxf(t, fmaxf(fmaxf(st[n][m][0], st[n][m][1]),
                                   fmaxf(st[n][m][2], st[n][m][3])));
            t = fmaxf(t, __shfl_xor(t, 16, 64));
            t = fmaxf(t, __shfl_xor(t, 32, 64));
            if (__any(t - mreg[m] > 11.5415603f)) {   // 8 * log2(e): rarely taken
                float nm = fmaxf(mreg[m], t);
                float fac = exp2f(mreg[m] - nm);
                mreg[m] = nm;
                lrun[m] *= fac;
                float fb[4];
#pragma unroll
                for (int j = 0; j < 4; ++j)
                    fb[j] = __shfl(fac, bcast + j, 64);
#pragma unroll
                for (int nd = 0; nd < 4; ++nd)
#pragma unroll
                    for (int j = 0; j < 4; ++j)
                        o[m][nd][j] *= fb[j];
            }
            float ps = 0.0f;
            const int r = m * 16 + lr;
#pragma unroll
            for (int n = 0; n < 4; ++n) {
                float p0 = exp2f(st[n][m][0] - mreg[m]);
                float p1 = exp2f(st[n][m][1] - mreg[m]);
                float p2 = exp2f(st[n][m][2] - mreg[m]);
                float p3 = exp2f(st[n][m][3] - mreg[m]);
                ps += (p0 + p1) + (p2 + p3);
                bf16x4 w;
                w[0] = (bf16_t)p0; w[1] = (bf16_t)p1; w[2] = (bf16_t)p2; w[3] = (bf16_t)p3;
                *(bf16x4*)((char*)sPw + r * 128 +
                           (((n * 2 + (hg >> 1)) ^ (r & 7)) << 4) + ((hg & 1) * 8)) = w;
            }
            ps += __shfl_xor(ps, 16, 64);
            ps += __shfl_xor(ps, 32, 64);
            lrun[m] += ps;
        }

        __builtin_amdgcn_s_setprio(1);
#pragma unroll
        for (int kf = 0; kf < 2; ++kf) {
            const int sl = kf ? sl1 : sl0;
            bf16x8 ap0 = *(const bf16x8*)((const char*)sPw + lr * 128 + sl);
            bf16x8 ap1 = *(const bf16x8*)((const char*)sPw + (16 + lr) * 128 + sl);
#pragma unroll
            for (int nd = 0; nd < 4; ++nd) {
                bf16x8 bv = *(const bf16x8*)((const char*)sVc + (nd * 16 + lr) * 128 + sl);
                o[0][nd] = __builtin_amdgcn_mfma_f32_16x16x32_bf16(ap0, bv, o[0][nd], 0, 0, 0);
                o[1][nd] = __builtin_amdgcn_mfma_f32_16x16x32_bf16(ap1, bv, o[1][nd], 0, 0, 0);
            }
        }
        __builtin_amdgcn_s_setprio(0);
    };

    const int NT = T_ / 64;   // 32, even
    stage(0, sK0, sV0);
    __syncthreads();
    for (int it = 0; it < NT; it += 2) {
        stage(it + 1, sK1, sV1);
        tile(sK0, sV0);
        __syncthreads();
        if (it + 2 < NT) stage(it + 2, sK0, sV0);
        tile(sK1, sV1);
        __syncthreads();
    }

    float lb[2][4];
#pragma unroll
    for (int m = 0; m < 2; ++m)
#pragma unroll
        for (int j = 0; j < 4; ++j)
            lb[m][j] = __shfl(lrun[m], bcast + j, 64);
#pragma unroll
    for (int m = 0; m < 2; ++m)
#pragma unroll
        for (int nd = 0; nd < 4; ++nd)
#pragma unroll
            for (int j = 0; j < 4; ++j) {
                int row = wr0 + m * 16 + hg * 4 + j;
                int col = nd * 16 + lr;
                float val = o[m][nd][j] / lb[m][j];
                outA[((size_t)(b * T_ + row)) * C_ + h * D_ + col] = __float2bfloat16(val);
            }
}

// ---------------- launch ----------------
extern "C" void kernel_launch(void* const* d_in, const int* in_sizes, int n_in,
                              void* d_out, int out_size, void* d_ws, size_t ws_size,
                              hipStream_t stream)
{
    const float* x    = (const float*)d_in[0];
    const float* Wq   = (const float*)d_in[1];
    const float* Wk   = (const float*)d_in[2];
    const float* Wv   = (const float*)d_in[3];
    const float* Wo   = (const float*)d_in[4];
    const float* bo   = (const float*)d_in[5];
    const float* ln1g = (const float*)d_in[6];
    const float* ln1b = (const float*)d_in[7];
    const float* ln2g = (const float*)d_in[8];
    const float* ln2b = (const float*)d_in[9];
    const float* W1   = (const float*)d_in[10];
    const float* b1   = (const float*)d_in[11];
    const float* W2   = (const float*)d_in[12];
    const float* b2   = (const float*)d_in[13];
    float* out = (float*)d_out;
    char* ws = (char*)d_ws;

    hbf*  xn    = (hbf*)(ws + 0);            // 12.58 MB
    hbf*  WqkT  = (hbf*)(ws + 12582912);     // [1536][768] 2.36 MB
    hbf*  WvT   = (hbf*)(ws + 14942208);     // [768][768]  1.18 MB
    hbf*  qb    = (hbf*)(ws + 16121856);     // 12.58 MB
    hbf*  kb    = (hbf*)(ws + 28704768);     // 12.58 MB
    hbf*  vT    = (hbf*)(ws + 41287680);     // [768][8192] 12.58 MB
    hbf*  h1    = (hbf*)(ws + 0);            // 50.33 MB overlay (dead inputs by MLP)
    hbf*  attnB = (hbf*)(ws + 53870592);     // 12.58 MB
    hbf*  yln   = (hbf*)(ws + 53870592);     // overlays attnB
    float* x2   = (float*)(ws + 66453504);   // 25.17 MB
    hbf*  WoT   = (hbf*)(ws + 91619328);     // 1.18 MB
    hbf*  W1T   = (hbf*)(ws + 92798976);     // 4.72 MB
    hbf*  W2T   = (hbf*)(ws + 97517568);     // 4.72 MB (end 102,236,160)

    const float SCALE2 = 0.036084391824351615f * 1.4426950408889634f;  // 768^-0.5 * log2(e)

    transpose_pack<<<dim3(1, 12, 12), 256, 0, stream>>>(Wq, WqkT, 768, 64);
    transpose_pack<<<dim3(1, 12, 12), 256, 0, stream>>>(Wk, WqkT + 768 * 768, 768, 64);
    transpose_pack<<<dim3(1, 12, 12), 256, 0, stream>>>(Wv, WvT, 768, 64);
    transpose_pack<<<dim3(12, 12, 1), 256, 0, stream>>>(Wo, WoT, 768, 768);
    transpose_pack<<<dim3(48, 12, 1), 256, 0, stream>>>(W1, W1T, 768, 3072);
    transpose_pack<<<dim3(12, 48, 1), 256, 0, stream>>>(W2, W2T, 3072, 768);
    ln_kernel<<<8192, 256, 0, stream>>>(x, ln1g, ln1b, xn);
    // q/k projections (N=1536)
    gemm_kernel<3><<<768, 256, 0, stream>>>(xn, WqkT, nullptr, nullptr, nullptr, nullptr,
        8192, 1536, 768, qb, kb, SCALE2, 12);
    // V^T: [hd][bt] = WvT[hd][c] . xn[bt][c]
    gemm_kernel<0><<<384, 256, 0, stream>>>(WvT, xn, nullptr, vT, nullptr, nullptr,
        768, BT_, 768, nullptr, nullptr, 1.0f, 64);
    attn_kernel<<<768, 256, 0, stream>>>(qb, kb, vT, attnB);
    gemm_kernel<1><<<384, 256, 0, stream>>>(attnB, WoT, x2, nullptr, bo, x,
        8192, 768, 768, nullptr, nullptr, 1.0f, 6);
    ln_kernel<<<8192, 256, 0, stream>>>(x2, ln2g, ln2b, yln);
    gemm_kernel<2><<<1536, 256, 0, stream>>>(yln, W1T, nullptr, h1, b1, nullptr,
        8192, 3072, 768, nullptr, nullptr, 1.0f, 24);
    gemm_kernel<1><<<384, 256, 0, stream>>>(h1, W2T, out, nullptr, b2, x2,
        8192, 768, 3072, nullptr, nullptr, 1.0f, 6);
}

// Round 6
// 303.198 us; speedup vs baseline: 1.5356x; 1.0678x over previous
//
#include <hip/hip_runtime.h>
#include <hip/hip_bf16.h>
#include <cstdint>
#include <cmath>

#define B_ 4
#define T_ 2048
#define C_ 768
#define H_ 12
#define D_ 64
#define MLP_ 3072
#define BT_ (B_*T_)

typedef __hip_bfloat16 hbf;
typedef __bf16 bf16_t;
typedef bf16_t bf16x8 __attribute__((ext_vector_type(8)));
typedef bf16_t bf16x4 __attribute__((ext_vector_type(4)));
typedef float f32x4 __attribute__((ext_vector_type(4)));

static __device__ __forceinline__ void load_lds16(const void* g, void* l) {
    __builtin_amdgcn_global_load_lds(
        (const __attribute__((address_space(1))) unsigned int*)g,
        (__attribute__((address_space(3))) unsigned int*)l, 16, 0, 0);
}

// ---------------- LDS-tiled transpose: f32 [R][S] -> bf16 [S][R] ----------------
__global__ __launch_bounds__(256) void transpose_pack(
    const float* __restrict__ src, hbf* __restrict__ dst, int R, int S)
{
    __shared__ float tl[64 * 65];
    src += (size_t)blockIdx.z * R * S;
    dst += (size_t)blockIdx.z * R * S;
    const int r0 = blockIdx.y * 64, s0 = blockIdx.x * 64;
    const int c = threadIdx.x & 63, q = threadIdx.x >> 6;
#pragma unroll
    for (int j = 0; j < 16; ++j) {
        int r = q + j * 4;
        tl[r * 65 + c] = src[(size_t)(r0 + r) * S + s0 + c];
    }
    __syncthreads();
#pragma unroll
    for (int j = 0; j < 16; ++j) {
        int s = q + j * 4;
        dst[(size_t)(s0 + s) * R + r0 + c] = __float2bfloat16(tl[c * 65 + s]);
    }
}

// ---------------- layernorm (row = 768) ----------------
__global__ __launch_bounds__(256) void ln_kernel(
    const float* __restrict__ x, const float* __restrict__ g,
    const float* __restrict__ bb, hbf* __restrict__ out)
{
    __shared__ float red[8];
    const int row = blockIdx.x;
    const float* xr = x + (size_t)row * C_;
    const int t = threadIdx.x;
    float v0 = xr[t], v1 = xr[t + 256], v2 = xr[t + 512];
    float s = v0 + v1 + v2;
    float s2 = v0 * v0 + v1 * v1 + v2 * v2;
#pragma unroll
    for (int m = 1; m < 64; m <<= 1) {
        s  += __shfl_xor(s,  m, 64);
        s2 += __shfl_xor(s2, m, 64);
    }
    if ((t & 63) == 0) { red[t >> 6] = s; red[4 + (t >> 6)] = s2; }
    __syncthreads();
    float S  = red[0] + red[1] + red[2] + red[3];
    float S2 = red[4] + red[5] + red[6] + red[7];
    float mu  = S * (1.0f / C_);
    float var = S2 * (1.0f / C_) - mu * mu;
    float inv = rsqrtf(var + 1e-6f);
    hbf* orow = out + (size_t)row * C_;
    orow[t]       = __float2bfloat16((v0 - mu) * inv * g[t]       + bb[t]);
    orow[t + 256] = __float2bfloat16((v1 - mu) * inv * g[t + 256] + bb[t + 256]);
    orow[t + 512] = __float2bfloat16((v2 - mu) * inv * g[t + 512] + bb[t + 512]);
}

// ---------------- GEMM: C[M,N] = A[M,K](bf16) * Bt[N,K](bf16)^T ----------------
// BK=64, 128x128 tile, XOR-swizzled LDS, 2-phase dbuf, 1D grid + XCD swizzle.
template<int EPI>
__global__ __launch_bounds__(256, 2) void gemm_kernel(
    const hbf* __restrict__ A, const hbf* __restrict__ Bt,
    float* __restrict__ outF, hbf* __restrict__ outH,
    const float* __restrict__ bias, const float* __restrict__ resid,
    int M, int N, int K,
    hbf* __restrict__ qb, hbf* __restrict__ kb,
    float scale, int gx)
{
    __shared__ hbf sA0[128 * 64], sA1[128 * 64];
    __shared__ hbf sB0[128 * 64], sB1[128 * 64];
    const int tid = threadIdx.x;
    const int lane = tid & 63;
    const int wid = tid >> 6;
    const int wm = wid >> 1, wn = wid & 1;
    const int lr = lane & 15, hg = lane >> 4;
    const int bid = blockIdx.x, nwg = gridDim.x;
    const int wg = (bid & 7) * (nwg >> 3) + (bid >> 3);
    const int bx = wg % gx, by = wg / gx;
    const int row0 = by * 128;
    const int col0 = bx * 128;

    f32x4 acc[4][4] = {};

    int offG[4];
    const int Kb = K * 2;
#pragma unroll
    for (int i = 0; i < 4; ++i) {
        int c = tid + i * 256;
        offG[i] = (c >> 3) * Kb + (((c & 7) ^ ((c >> 3) & 7)) << 4);
    }
    const char* gA = (const char*)(A + (size_t)row0 * K);
    const char* gB = (const char*)(Bt + (size_t)col0 * K);

    auto stage = [&](int kt, hbf* sAd, hbf* sBd) {
        const int kb2 = kt * 128;
#pragma unroll
        for (int i = 0; i < 4; ++i) {
            load_lds16(gA + (size_t)(offG[i] + kb2), (char*)sAd + i * 4096 + wid * 1024);
            load_lds16(gB + (size_t)(offG[i] + kb2), (char*)sBd + i * 4096 + wid * 1024);
        }
    };
    auto compute = [&](const hbf* sAc, const hbf* sBc) {
#pragma unroll
        for (int kf = 0; kf < 2; ++kf) {
            const int sl = ((kf * 4 + hg) ^ (lr & 7)) << 4;
            bf16x8 af[4], bfr[4];
#pragma unroll
            for (int m = 0; m < 4; ++m)
                af[m] = *(const bf16x8*)((const char*)sAc + (wm * 64 + m * 16 + lr) * 128 + sl);
#pragma unroll
            for (int n = 0; n < 4; ++n)
                bfr[n] = *(const bf16x8*)((const char*)sBc + (wn * 64 + n * 16 + lr) * 128 + sl);
#pragma unroll
            for (int m = 0; m < 4; ++m)
#pragma unroll
                for (int n = 0; n < 4; ++n)
                    acc[m][n] = __builtin_amdgcn_mfma_f32_16x16x32_bf16(af[m], bfr[n], acc[m][n], 0, 0, 0);
        }
    };

    const int NK = K >> 6;
    stage(0, sA0, sB0);
    __syncthreads();
    for (int kt = 0; kt < NK; kt += 2) {
        stage(kt + 1, sA1, sB1);
        compute(sA0, sB0);
        __syncthreads();
        if (kt + 2 < NK) stage(kt + 2, sA0, sB0);
        compute(sA1, sB1);
        __syncthreads();
    }

#pragma unroll
    for (int m = 0; m < 4; ++m) {
#pragma unroll
        for (int n = 0; n < 4; ++n) {
#pragma unroll
            for (int j = 0; j < 4; ++j) {
                int row = row0 + wm * 64 + m * 16 + hg * 4 + j;
                int col = col0 + wn * 64 + n * 16 + lr;
                float v = acc[m][n][j];
                if constexpr (EPI == 0) {
                    outH[(size_t)row * N + col] = __float2bfloat16(v);
                } else if constexpr (EPI == 1) {
                    outF[(size_t)row * N + col] = v + bias[col] + resid[(size_t)row * N + col];
                } else if constexpr (EPI == 2) {
                    float tt = v + bias[col];
                    float ge = 0.5f * tt * (1.0f + erff(tt * 0.70710678118654752f));
                    outH[(size_t)row * N + col] = __float2bfloat16(ge);
                } else {
                    int typ = col / C_;            // 0=q, 1=k
                    int rr = col - typ * C_;
                    int h = rr >> 6, d = rr & 63;
                    int b = row >> 11, t = row & (T_ - 1);
                    size_t bh = (size_t)b * H_ + h;
                    if (typ == 0) qb[(bh * T_ + t) * D_ + d] = __float2bfloat16(v * scale);
                    else          kb[(bh * T_ + t) * D_ + d] = __float2bfloat16(v);
                }
            }
        }
    }
}

// ---------------- flash attention (swapped QK^T, defer-max, __expf) ------------
// 1D grid 768 (XCD-swizzled, bh-major). 4 waves x 32 q-rows. q pre-scaled by
// 768^-0.5. vT is [hd=768][B*T=8192].
__global__ __launch_bounds__(256, 3) void attn_kernel(
    const hbf* __restrict__ qg, const hbf* __restrict__ kg,
    const hbf* __restrict__ vg, hbf* __restrict__ outA)
{
    __shared__ hbf sK0[64 * 64], sK1[64 * 64];   // [s][d], swizzled
    __shared__ hbf sV0[64 * 64], sV1[64 * 64];   // [d][s], swizzled
    __shared__ hbf sP[4 * 32 * 64];              // per wave [q=32][kv=64], swizzled
    const int tid = threadIdx.x, lane = tid & 63, wid = tid >> 6;
    const int lr = lane & 15, hg = lane >> 4;
    const int wg = (blockIdx.x & 7) * 96 + (blockIdx.x >> 3);   // 768/8 = 96
    const int bh = wg >> 4;
    const int b = bh / H_, h = bh - b * H_;
    const int wr0 = (wg & 15) * 128 + wid * 32;
    const hbf* qbh = qg + (size_t)bh * T_ * D_;
    const hbf* kbh = kg + (size_t)bh * T_ * D_;
    const hbf* vbh = vg + (size_t)h * 64 * BT_ + (size_t)b * T_;

    bf16x8 a_q[2][2];
#pragma unroll
    for (int m = 0; m < 2; ++m)
#pragma unroll
        for (int kf = 0; kf < 2; ++kf)
            a_q[m][kf] = *(const bf16x8*)(qbh + (size_t)(wr0 + m * 16 + lr) * D_ + kf * 32 + hg * 8);

    f32x4 o[2][4] = {};
    float mreg[2] = {-3e38f, -3e38f};
    float lrun[2] = {0.0f, 0.0f};

    int offK[2], offV[2];
#pragma unroll
    for (int i = 0; i < 2; ++i) {
        int c = tid + i * 256;
        int sw = ((c & 7) ^ ((c >> 3) & 7)) << 4;
        offK[i] = (c >> 3) * 128 + sw;
        offV[i] = (c >> 3) * (BT_ * 2) + sw;
    }
    hbf* sPw = sP + wid * (32 * 64);
    const int sl0 = ((0 * 4 + hg) ^ (lr & 7)) << 4;
    const int sl1 = ((1 * 4 + hg) ^ (lr & 7)) << 4;
    const int bcast = hg * 20;

    auto stage = [&](int itn, hbf* sKd, hbf* sVd) {
        const char* kp = (const char*)kbh + (size_t)itn * 8192;
        const char* vp = (const char*)vbh + (size_t)itn * 128;
#pragma unroll
        for (int i = 0; i < 2; ++i) {
            load_lds16(kp + offK[i], (char*)sKd + i * 4096 + wid * 1024);
            load_lds16(vp + offV[i], (char*)sVd + i * 4096 + wid * 1024);
        }
    };

    auto tile = [&](const hbf* sKc, const hbf* sVc) {
        f32x4 st[4][2] = {};
        __builtin_amdgcn_s_setprio(1);
#pragma unroll
        for (int kf = 0; kf < 2; ++kf) {
            const int sl = kf ? sl1 : sl0;
#pragma unroll
            for (int n = 0; n < 4; ++n) {
                bf16x8 ak = *(const bf16x8*)((const char*)sKc + (n * 16 + lr) * 128 + sl);
                st[n][0] = __builtin_amdgcn_mfma_f32_16x16x32_bf16(ak, a_q[0][kf], st[n][0], 0, 0, 0);
                st[n][1] = __builtin_amdgcn_mfma_f32_16x16x32_bf16(ak, a_q[1][kf], st[n][1], 0, 0, 0);
            }
        }
        __builtin_amdgcn_s_setprio(0);

#pragma unroll
        for (int m = 0; m < 2; ++m) {
            float t = st[0][m][0];
#pragma unroll
            for (int n = 0; n < 4; ++n)
#pragma unroll
                for (int j = 0; j < 4; ++j)
                    if (n + j > 0) t = fmaxf(t, st[n][m][j]);   // fuseable max3 chain
            t = fmaxf(t, __shfl_xor(t, 16, 64));
            t = fmaxf(t, __shfl_xor(t, 32, 64));
            if (__any(t - mreg[m] > 8.0f)) {       // defer-max: rarely taken
                float nm = fmaxf(mreg[m], t);
                float fac = __expf(mreg[m] - nm);
                mreg[m] = nm;
                lrun[m] *= fac;
                float fb[4];
#pragma unroll
                for (int j = 0; j < 4; ++j)
                    fb[j] = __shfl(fac, bcast + j, 64);
#pragma unroll
                for (int nd = 0; nd < 4; ++nd)
#pragma unroll
                    for (int j = 0; j < 4; ++j)
                        o[m][nd][j] *= fb[j];
            }
            float ps = 0.0f;
            const int r = m * 16 + lr;
#pragma unroll
            for (int n = 0; n < 4; ++n) {
                float p0 = __expf(st[n][m][0] - mreg[m]);
                float p1 = __expf(st[n][m][1] - mreg[m]);
                float p2 = __expf(st[n][m][2] - mreg[m]);
                float p3 = __expf(st[n][m][3] - mreg[m]);
                ps += (p0 + p1) + (p2 + p3);
                bf16x4 w;
                w[0] = (bf16_t)p0; w[1] = (bf16_t)p1; w[2] = (bf16_t)p2; w[3] = (bf16_t)p3;
                *(bf16x4*)((char*)sPw + r * 128 +
                           (((n * 2 + (hg >> 1)) ^ (r & 7)) << 4) + ((hg & 1) * 8)) = w;
            }
            ps += __shfl_xor(ps, 16, 64);
            ps += __shfl_xor(ps, 32, 64);
            lrun[m] += ps;
        }

        __builtin_amdgcn_s_setprio(1);
#pragma unroll
        for (int kf = 0; kf < 2; ++kf) {
            const int sl = kf ? sl1 : sl0;
            bf16x8 ap0 = *(const bf16x8*)((const char*)sPw + lr * 128 + sl);
            bf16x8 ap1 = *(const bf16x8*)((const char*)sPw + (16 + lr) * 128 + sl);
#pragma unroll
            for (int nd = 0; nd < 4; ++nd) {
                bf16x8 bv = *(const bf16x8*)((const char*)sVc + (nd * 16 + lr) * 128 + sl);
                o[0][nd] = __builtin_amdgcn_mfma_f32_16x16x32_bf16(ap0, bv, o[0][nd], 0, 0, 0);
                o[1][nd] = __builtin_amdgcn_mfma_f32_16x16x32_bf16(ap1, bv, o[1][nd], 0, 0, 0);
            }
        }
        __builtin_amdgcn_s_setprio(0);
    };

    const int NT = T_ / 64;   // 32, even
    stage(0, sK0, sV0);
    __syncthreads();
    for (int it = 0; it < NT; it += 2) {
        stage(it + 1, sK1, sV1);
        tile(sK0, sV0);
        __syncthreads();
        if (it + 2 < NT) stage(it + 2, sK0, sV0);
        tile(sK1, sV1);
        __syncthreads();
    }

    float lb[2][4];
#pragma unroll
    for (int m = 0; m < 2; ++m)
#pragma unroll
        for (int j = 0; j < 4; ++j)
            lb[m][j] = __shfl(lrun[m], bcast + j, 64);
#pragma unroll
    for (int m = 0; m < 2; ++m)
#pragma unroll
        for (int nd = 0; nd < 4; ++nd)
#pragma unroll
            for (int j = 0; j < 4; ++j) {
                int row = wr0 + m * 16 + hg * 4 + j;
                int col = nd * 16 + lr;
                float val = o[m][nd][j] / lb[m][j];
                outA[((size_t)(b * T_ + row)) * C_ + h * D_ + col] = __float2bfloat16(val);
            }
}

// ---------------- launch ----------------
extern "C" void kernel_launch(void* const* d_in, const int* in_sizes, int n_in,
                              void* d_out, int out_size, void* d_ws, size_t ws_size,
                              hipStream_t stream)
{
    const float* x    = (const float*)d_in[0];
    const float* Wq   = (const float*)d_in[1];
    const float* Wk   = (const float*)d_in[2];
    const float* Wv   = (const float*)d_in[3];
    const float* Wo   = (const float*)d_in[4];
    const float* bo   = (const float*)d_in[5];
    const float* ln1g = (const float*)d_in[6];
    const float* ln1b = (const float*)d_in[7];
    const float* ln2g = (const float*)d_in[8];
    const float* ln2b = (const float*)d_in[9];
    const float* W1   = (const float*)d_in[10];
    const float* b1   = (const float*)d_in[11];
    const float* W2   = (const float*)d_in[12];
    const float* b2   = (const float*)d_in[13];
    float* out = (float*)d_out;
    char* ws = (char*)d_ws;

    hbf*  xn    = (hbf*)(ws + 0);            // 12.58 MB
    hbf*  WqkT  = (hbf*)(ws + 12582912);     // [1536][768] 2.36 MB
    hbf*  WvT   = (hbf*)(ws + 14942208);     // [768][768]  1.18 MB
    hbf*  qb    = (hbf*)(ws + 16121856);     // 12.58 MB
    hbf*  kb    = (hbf*)(ws + 28704768);     // 12.58 MB
    hbf*  vT    = (hbf*)(ws + 41287680);     // [768][8192] 12.58 MB
    hbf*  h1    = (hbf*)(ws + 0);            // 50.33 MB overlay (dead inputs by MLP)
    hbf*  attnB = (hbf*)(ws + 53870592);     // 12.58 MB
    hbf*  yln   = (hbf*)(ws + 53870592);     // overlays attnB
    float* x2   = (float*)(ws + 66453504);   // 25.17 MB
    hbf*  WoT   = (hbf*)(ws + 91619328);     // 1.18 MB
    hbf*  W1T   = (hbf*)(ws + 92798976);     // 4.72 MB
    hbf*  W2T   = (hbf*)(ws + 97517568);     // 4.72 MB (end 102,236,160)

    const float SCALE = 0.036084391824351615f;  // 768^-0.5

    transpose_pack<<<dim3(1, 12, 12), 256, 0, stream>>>(Wq, WqkT, 768, 64);
    transpose_pack<<<dim3(1, 12, 12), 256, 0, stream>>>(Wk, WqkT + 768 * 768, 768, 64);
    transpose_pack<<<dim3(1, 12, 12), 256, 0, stream>>>(Wv, WvT, 768, 64);
    transpose_pack<<<dim3(12, 12, 1), 256, 0, stream>>>(Wo, WoT, 768, 768);
    transpose_pack<<<dim3(48, 12, 1), 256, 0, stream>>>(W1, W1T, 768, 3072);
    transpose_pack<<<dim3(12, 48, 1), 256, 0, stream>>>(W2, W2T, 3072, 768);
    ln_kernel<<<8192, 256, 0, stream>>>(x, ln1g, ln1b, xn);
    gemm_kernel<3><<<768, 256, 0, stream>>>(xn, WqkT, nullptr, nullptr, nullptr, nullptr,
        8192, 1536, 768, qb, kb, SCALE, 12);
    gemm_kernel<0><<<384, 256, 0, stream>>>(WvT, xn, nullptr, vT, nullptr, nullptr,
        768, BT_, 768, nullptr, nullptr, 1.0f, 64);
    attn_kernel<<<768, 256, 0, stream>>>(qb, kb, vT, attnB);
    gemm_kernel<1><<<384, 256, 0, stream>>>(attnB, WoT, x2, nullptr, bo, x,
        8192, 768, 768, nullptr, nullptr, 1.0f, 6);
    ln_kernel<<<8192, 256, 0, stream>>>(x2, ln2g, ln2b, yln);
    gemm_kernel<2><<<1536, 256, 0, stream>>>(yln, W1T, nullptr, h1, b1, nullptr,
        8192, 3072, 768, nullptr, nullptr, 1.0f, 24);
    gemm_kernel<1><<<384, 256, 0, stream>>>(h1, W2T, out, nullptr, b2, x2,
        8192, 768, 3072, nullptr, nullptr, 1.0f, 6);
}